// Round 10
// baseline (182.459 us; speedup 1.0000x reference)
//
#include <hip/hip_runtime.h>

#define B_ 8
#define M_ 32
#define C_ 512
#define H_ 64
#define W_ 64
#define HW 4096
#define NKT 16
#define KC 32
// gcm tile
#define TW 4
#define TH 4
#define NPOS 16
#define PW 6
#define PH 6
#define NPM 36
// padded m grid
#define HP 66
#define WP 66
#define HPWP (HP*WP)
// prep LDS geometry (u32 units): slab s=(row*2+img) stride 1092; within: ckpair*68 + w
#define SLAB 1092
#define CKS 68

typedef __attribute__((ext_vector_type(8))) short short8;
typedef __attribute__((ext_vector_type(4))) float float4v;
typedef __attribute__((ext_vector_type(4))) unsigned uint4v;

static __device__ __forceinline__ unsigned pk_bf16(float lo, float hi) {
    unsigned r;
    asm("v_cvt_pk_bf16_f32 %0, %1, %2" : "=v"(r) : "v"(lo), "v"(hi));
    return r;
}

static __device__ __forceinline__ void load_lds16(const short* g, short* l) {
    __builtin_amdgcn_global_load_lds((const __attribute__((address_space(1))) void*)g,
                                     (__attribute__((address_space(3))) void*)l, 16, 0, 0);
}

// ---------- prep v6: 1KB read runs + line-covering stores + partial-slot norms ----------
// blocks 0..255   : q (pr = g>>6 of 4,  hq = (g>>2)&15, ktg = g&3)
// blocks 256..1279: m (pr of 16, hq, ktg)
__global__ __launch_bounds__(512)
void prep_kernel(const float* __restrict__ Q, const float* __restrict__ Mb,
                 short* __restrict__ qT, short* __restrict__ mT,
                 float* __restrict__ nqp, float* __restrict__ nmp) {
    __shared__ __align__(16) unsigned buf[2][8 * SLAB];   // 2 x 34.9 KB

    const int tid = threadIdx.x;
    const bool isq = (blockIdx.x < 256);
    const int g  = isq ? (int)blockIdx.x : (int)blockIdx.x - 256;
    const int pr  = g >> 6;
    const int hq  = (g >> 2) & 15;
    const int ktg = g & 3;
    const float* base = (isq ? Q : Mb) + (size_t)(pr * 2) * C_ * HW;

    // ---- load / LDS-write roles: lane lw covers a 4-row x 64-px slab (1 KB/instr) ----
    const int lw = tid & 63;          // w4 = lw&15, lrow = lw>>4
    const int w4 = lw & 15, lrow = lw >> 4;
    const int cpair = tid >> 6;       // wave id 0..7
    const float* lsrc0 = base + (size_t)(ktg * 128 + cpair * 2) * HW + hq * 4 * W_ + lw * 4;

    // ---- LDS-gather / global-store roles: wave store = contiguous 1 KB, full lines ----
    const int sckq = tid & 3, sim = (tid >> 2) & 1, srw = tid >> 3;   // srw 0..63

    float4v ssq0 = {0.f,0.f,0.f,0.f}, ssq1 = ssq0;
    float4v V000, V001, V010, V011, V100, V101, V110, V111;

#define LOADP(ch) { const float* p_ = lsrc0 + (size_t)(ch) * 32 * HW; \
    V000 = *(const float4v*)(p_);                         V001 = *(const float4v*)(p_ + HW); \
    V010 = *(const float4v*)(p_ + 16 * HW);               V011 = *(const float4v*)(p_ + 17 * HW); \
    const float* q_ = p_ + (size_t)C_ * HW; \
    V100 = *(const float4v*)(q_);                         V101 = *(const float4v*)(q_ + HW); \
    V110 = *(const float4v*)(q_ + 16 * HW);               V111 = *(const float4v*)(q_ + 17 * HW); }

#define WRITEP(bs) { \
    ssq0 += V000 * V000 + V001 * V001 + V010 * V010 + V011 * V011; \
    ssq1 += V100 * V100 + V101 * V101 + V110 * V110 + V111 * V111; \
    uint4v t0, t1, t2, t3; \
    _Pragma("unroll") \
    for (int j = 0; j < 4; ++j) { \
        t0[j] = pk_bf16(V000[j], V001[j]); t1[j] = pk_bf16(V010[j], V011[j]); \
        t2[j] = pk_bf16(V100[j], V101[j]); t3[j] = pk_bf16(V110[j], V111[j]); } \
    unsigned* b_ = &buf[bs][0]; \
    *(uint4v*)&b_[(lrow * 2 + 0) * SLAB + (cpair    ) * CKS + w4 * 4] = t0; \
    *(uint4v*)&b_[(lrow * 2 + 0) * SLAB + (cpair + 8) * CKS + w4 * 4] = t1; \
    *(uint4v*)&b_[(lrow * 2 + 1) * SLAB + (cpair    ) * CKS + w4 * 4] = t2; \
    *(uint4v*)&b_[(lrow * 2 + 1) * SLAB + (cpair + 8) * CKS + w4 * 4] = t3; }

#define STOREP(ch, bs) { \
    _Pragma("unroll") \
    for (int srow = 0; srow < 4; ++srow) { \
        const unsigned* rp = &buf[bs][(srow * 2 + sim) * SLAB + srw]; \
        union { unsigned u[4]; short8 s; } o_; \
        _Pragma("unroll") \
        for (int j = 0; j < 4; ++j) o_.u[j] = rp[(sckq * 4 + j) * CKS]; \
        short* d_; \
        if (isq) d_ = qT + (((size_t)(ktg * 4 + (ch)) * HW + (size_t)(hq * 4 + srow) * 64 + srw) * B_ \
                            + pr * 2 + sim) * KC + sckq * 8; \
        else     d_ = mT + (((size_t)(ktg * 4 + (ch)) * HPWP + (size_t)(hq * 4 + srow + 1) * WP + srw + 1) * M_ \
                            + pr * 2 + sim) * KC + sckq * 8; \
        *(short8*)d_ = o_.s; } }

    LOADP(0); WRITEP(0); __syncthreads();
    LOADP(1); STOREP(0, 0); WRITEP(1); __syncthreads();
    LOADP(2); STOREP(1, 1); WRITEP(0); __syncthreads();
    LOADP(3); STOREP(2, 0); WRITEP(1); __syncthreads();
    // last chunk: consume buf1; stash norm partials in buf0 (disjoint)
    {
        float* redf = (float*)&buf[0][0];   // 4096 floats = 16 KB
        *(float4v*)&redf[(((cpair * 2 + 0) * 4 + lrow) * 16 + w4) * 4] = ssq0;
        *(float4v*)&redf[(((cpair * 2 + 1) * 4 + lrow) * 16 + w4) * 4] = ssq1;
    }
    STOREP(3, 1);
    __syncthreads();

    // ---- norms: sum 8 cpair partials, write to per-ktg slot (no atomics) ----
    {
        const float* redf = (const float*)&buf[0][0];
        const int rim2 = tid >> 8, rrow = (tid >> 6) & 3, rw_ = tid & 63;
        float t = 0.f;
        #pragma unroll
        for (int cp = 0; cp < 8; ++cp)
            t += redf[(((cp * 2 + rim2) * 4 + rrow) * 16 + (rw_ >> 2)) * 4 + (rw_ & 3)];
        const int img = pr * 2 + rim2;
        const int pix = (hq * 4 + rrow) * 64 + rw_;
        if (isq) nqp[((size_t)ktg * B_ + img) * HW + pix] = t;
        else     nmp[((size_t)ktg * M_ + img) * HW + pix] = t;
    }

    // ---- m-blocks: zero halo-ring slices (this block's rows/kts, its pr 128B slice) ----
    if (!isq) {
        short8 z = (short8){0, 0, 0, 0, 0, 0, 0, 0};
        if (tid < 256) {            // cols 0 & 65, rows hq*4+1..+4, kts ktg*4..+3
            int e = tid & 7, cell = tid >> 3;
            int kk = cell & 3, rr = (cell >> 2) & 3, cs = cell >> 4;
            size_t pos2 = (size_t)(hq * 4 + 1 + rr) * WP + (cs ? 65 : 0);
            *(short8*)(mT + (((size_t)(ktg * 4 + kk) * HPWP + pos2) * M_ + pr * 2) * KC + e * 8) = z;
        }
        if (hq == 0 || hq == 15) {  // full pad rows 0 / 65 for this ktg
            int row = (hq == 0) ? 0 : 65;
            for (int j = tid; j < 66 * 4 * 8; j += 512) {
                int e = j & 7, cell = j >> 3;
                int kk = cell & 3, col = cell >> 2;
                *(short8*)(mT + (((size_t)(ktg * 4 + kk) * HPWP + (size_t)row * WP + col) * M_ + pr * 2) * KC
                           + e * 8) = z;
            }
        }
    }
#undef LOADP
#undef WRITEP
#undef STOREP
}

// ---------- gcm: MFMA on raw bf16, partial-slot rsqrt epilogue ----------
__global__ __launch_bounds__(1024)
void gcm_kernel(const short* __restrict__ qT, const short* __restrict__ mT,
                const float* __restrict__ nqp, const float* __restrict__ nmp,
                float* __restrict__ out) {
    __shared__ __align__(16) short m_lds[NPM * M_ * KC];   // 72 KB
    __shared__ __align__(16) short q_lds[NPOS * 16 * KC];  // 16 KB

    const int tid = threadIdx.x;
    const int bx = blockIdx.x & 15, by = blockIdx.x >> 4;
    const int w0 = bx * TW, h0 = by * TH;
    const int wid = tid >> 6, lane = tid & 63;
    const int lw = wid & 3, lh = wid >> 2;
    const int col = lane & 15, kg = lane >> 4;
    const int mypos = lh * TW + lw;
    const int gh = h0 + lh, gw = w0 + lw;

    {
        short8 z = (short8){0, 0, 0, 0, 0, 0, 0, 0};
        *(short8*)&q_lds[tid * 8] = z;
    }

    float4v acc[9][2];
    #pragma unroll
    for (int d = 0; d < 9; ++d)
        #pragma unroll
        for (int hf = 0; hf < 2; ++hf)
            acc[d][hf] = (float4v){0.f, 0.f, 0.f, 0.f};

    for (int kt = 0; kt < NKT; ++kt) {
        __syncthreads();
        if (tid < 512) {
            int chunk = tid & 3, b = (tid >> 2) & 7, pidx = tid >> 5;
            int qh = h0 + (pidx >> 2), qw = w0 + (pidx & 3);
            const short* src = qT + (((size_t)kt * HW + qh * W_ + qw) * B_ + b) * KC + chunk * 8;
            *(short8*)&q_lds[pidx * 512 + b * KC + chunk * 8] = *(const short8*)src;
        }
        for (int j = wid; j < NPM * 2; j += 16) {
            int pm = j >> 1, half = j & 1;
            int ph = pm / PW, pw = pm % PW;
            size_t pos2 = (size_t)(h0 + ph) * WP + (w0 + pw);
            const short* gsrc = mT + ((size_t)kt * HPWP + pos2) * (M_ * KC)
                              + half * 512 + (size_t)lane * 8;
            short* ldst = m_lds + pm * 1024 + half * 512;
            load_lds16(gsrc, ldst);
        }
        __syncthreads();
        short8 aq = *(const short8*)&q_lds[mypos * 512 + col * KC + kg * 8];
        #pragma unroll
        for (int dh = 0; dh < 3; ++dh)
            #pragma unroll
            for (int dw = 0; dw < 3; ++dw) {
                const int pm = (lh + dh) * PW + (lw + dw);
                #pragma unroll
                for (int hf = 0; hf < 2; ++hf) {
                    short8 bm = *(const short8*)&m_lds[pm * 1024 + (hf * 16 + col) * KC + kg * 8];
                    acc[dh * 3 + dw][hf] =
                        __builtin_amdgcn_mfma_f32_16x16x32_bf16(aq, bm, acc[dh * 3 + dw][hf], 0, 0, 0);
                }
            }
    }

    float iq[4];
    #pragma unroll
    for (int r = 0; r < 4; ++r) {
        int b = (kg & 1) * 4 + r;
        float ss = 0.f;
        #pragma unroll
        for (int k = 0; k < 4; ++k)
            ss += nqp[((size_t)k * B_ + b) * HW + gh * W_ + gw];
        iq[r] = 1.0f / fmaxf(sqrtf(ss), 1e-12f);
    }
    float im[2][9];
    #pragma unroll
    for (int dh = 0; dh < 3; ++dh)
        #pragma unroll
        for (int dw = 0; dw < 3; ++dw) {
            int hh = min(63, max(0, gh + dh - 1));
            int ww = min(63, max(0, gw + dw - 1));
            #pragma unroll
            for (int hf = 0; hf < 2; ++hf) {
                int mi = hf * 16 + col;
                float ss = 0.f;
                #pragma unroll
                for (int k = 0; k < 4; ++k)
                    ss += nmp[((size_t)k * M_ + mi) * HW + hh * W_ + ww];
                im[hf][dh * 3 + dw] = 1.0f / fmaxf(sqrtf(ss), 1e-12f);
            }
        }
    float res[4];
    #pragma unroll
    for (int r = 0; r < 4; ++r) {
        float v0 = -1e30f, v1 = -1e30f;
        #pragma unroll
        for (int d = 0; d < 9; ++d) {
            v0 = fmaxf(v0, acc[d][0][r] * im[0][d]);
            v1 = fmaxf(v1, acc[d][1][r] * im[1][d]);
        }
        res[r] = fmaxf(v0 * iq[r], 0.f) + fmaxf(v1 * iq[r], 0.f);
    }
    #pragma unroll
    for (int mask = 1; mask < 16; mask <<= 1)
        #pragma unroll
        for (int r = 0; r < 4; ++r)
            res[r] += __shfl_xor(res[r], mask);

    if (col == 0 && kg < 2) {
        #pragma unroll
        for (int r = 0; r < 4; ++r) {
            int b = kg * 4 + r;
            out[(size_t)b * HW + gh * W_ + gw] = 1.0f - res[r] * (1.0f / M_);
        }
    }
}

extern "C" void kernel_launch(void* const* d_in, const int* in_sizes, int n_in,
                              void* d_out, int out_size, void* d_ws, size_t ws_size,
                              hipStream_t stream) {
    const float* Q  = (const float*)d_in[0];
    const float* Mb = (const float*)d_in[1];
    float* out = (float*)d_out;

    const size_t MT_SHORTS = (size_t)NKT * HPWP * M_ * KC;   // 71,368,704
    const size_t QT_SHORTS = (size_t)NKT * HW * B_ * KC;     // 16,777,216
    short* mT = (short*)d_ws;
    short* qT = mT + MT_SHORTS;
    float* nqp = (float*)(qT + QT_SHORTS);                   // [4][8][4096]
    float* nmp = nqp + 4 * B_ * HW;                          // [4][32][4096]

    prep_kernel<<<1280, 512, 0, stream>>>(Q, Mb, qT, mT, nqp, nmp);
    gcm_kernel<<<256, 1024, 0, stream>>>(qT, mT, nqp, nmp, out);
}